// Round 1
// baseline (673.899 us; speedup 1.0000x reference)
//
#include <hip/hip_runtime.h>
#include <math.h>

#define L_SEQ 1024
#define D_HEAD 64
#define N_EMB 1024
#define N_HD 512
#define N_BH 16
#define N_ITERS 20
#define R_INIT 20.0f   // safe shift: |logits| << 20 for these N(0,1)-scale inputs

// ---------------- init r/c ----------------
__global__ void init_rc(float* __restrict__ r, float* __restrict__ c) {
    int i = blockIdx.x * 256 + threadIdx.x;
    if (i < N_BH * L_SEQ) { r[i] = R_INIT; c[i] = 0.0f; }
}

// ---------------- generic 64x64-tile fp32 GEMM ----------------
// C = A(MxK) @ B(KxN) + bias(N)
// MODE 0: plain row-major store. MODE 1: qkv scatter ((b,l),(h,d)) -> [bh][l][d]
template <int MODE>
__device__ __forceinline__ void gemm_body(
    const float* __restrict__ A, const float* __restrict__ B,
    const float* __restrict__ bias, float* __restrict__ C,
    int N, int K)
{
    __shared__ float AsT[16][68];  // [k][m], pad 68: write-conflicts <= 2-way (free)
    __shared__ float Bs[16][68];   // [k][n]
    const int t = threadIdx.x;
    const int tx = t & 15, ty = t >> 4;
    const int m0 = blockIdx.y << 6, n0 = blockIdx.x << 6;
    const int arow = t >> 2, ak = (t & 3) << 2;
    const int brow = t >> 4, bc = (t & 15) << 2;
    float acc[4][4] = {};
    for (int k0 = 0; k0 < K; k0 += 16) {
        float4 av = *(const float4*)&A[(size_t)(m0 + arow) * K + k0 + ak];
        float4 bv = *(const float4*)&B[(size_t)(k0 + brow) * N + n0 + bc];
        __syncthreads();   // previous compute must finish before overwrite
        AsT[ak + 0][arow] = av.x;
        AsT[ak + 1][arow] = av.y;
        AsT[ak + 2][arow] = av.z;
        AsT[ak + 3][arow] = av.w;
        *(float4*)&Bs[brow][bc] = bv;
        __syncthreads();
#pragma unroll
        for (int kk = 0; kk < 16; ++kk) {
            float4 a = *(const float4*)&AsT[kk][ty << 2];
            float4 b = *(const float4*)&Bs[kk][tx << 2];
            acc[0][0] += a.x * b.x; acc[0][1] += a.x * b.y; acc[0][2] += a.x * b.z; acc[0][3] += a.x * b.w;
            acc[1][0] += a.y * b.x; acc[1][1] += a.y * b.y; acc[1][2] += a.y * b.z; acc[1][3] += a.y * b.w;
            acc[2][0] += a.z * b.x; acc[2][1] += a.z * b.y; acc[2][2] += a.z * b.z; acc[2][3] += a.z * b.w;
            acc[3][0] += a.w * b.x; acc[3][1] += a.w * b.y; acc[3][2] += a.w * b.z; acc[3][3] += a.w * b.w;
        }
    }
    float4 bi = *(const float4*)&bias[n0 + (tx << 2)];
#pragma unroll
    for (int i = 0; i < 4; ++i) {
        int m = m0 + (ty << 2) + i;
        float4 o;
        o.x = acc[i][0] + bi.x; o.y = acc[i][1] + bi.y;
        o.z = acc[i][2] + bi.z; o.w = acc[i][3] + bi.w;
        if (MODE == 0) {
            *(float4*)&C[(size_t)m * N + n0 + (tx << 2)] = o;
        } else {
            int b = m >> 10, l = m & 1023, h = n0 >> 6;
            *(float4*)&C[(size_t)(((b << 3) + h) * L_SEQ + l) * D_HEAD + (tx << 2)] = o;
        }
    }
}

__global__ __launch_bounds__(256) void gemm_qkv(
    const float* __restrict__ x,
    const float* __restrict__ Wq, const float* __restrict__ bq,
    const float* __restrict__ Wk, const float* __restrict__ bk,
    const float* __restrict__ Wv, const float* __restrict__ bv,
    float* __restrict__ q, float* __restrict__ k, float* __restrict__ v)
{
    const float* B; const float* bias; float* C;
    if (blockIdx.z == 0)      { B = Wq; bias = bq; C = q; }
    else if (blockIdx.z == 1) { B = Wk; bias = bk; C = k; }
    else                      { B = Wv; bias = bv; C = v; }
    gemm_body<1>(x, B, bias, C, N_HD, N_EMB);
}

__global__ __launch_bounds__(256) void gemm_out(
    const float* __restrict__ A, const float* __restrict__ Wo,
    const float* __restrict__ bo, float* __restrict__ C)
{
    gemm_body<0>(A, Wo, bo, C, N_EMB, N_HD);
}

// ---------------- logits = q @ k^T / 8 per (b,h) ----------------
__global__ __launch_bounds__(256) void logits_qkT(
    const float* __restrict__ q, const float* __restrict__ k,
    float* __restrict__ logits)
{
    const int bh = blockIdx.z;
    const int m0 = blockIdx.y << 6, n0 = blockIdx.x << 6;
    __shared__ float Qs[64][68];
    __shared__ float Ks[64][68];
    const int t = threadIdx.x;
    const int tx = t & 15, ty = t >> 4;
    const int lrow = t >> 4, ld4 = (t & 15) << 2;
#pragma unroll
    for (int rr = 0; rr < 4; ++rr) {
        int row = lrow + (rr << 4);
        *(float4*)&Qs[row][ld4] = *(const float4*)&q[(size_t)(bh * L_SEQ + m0 + row) * D_HEAD + ld4];
        *(float4*)&Ks[row][ld4] = *(const float4*)&k[(size_t)(bh * L_SEQ + n0 + row) * D_HEAD + ld4];
    }
    __syncthreads();
    float acc[4][4] = {};
#pragma unroll
    for (int d = 0; d < 64; d += 4) {
        float4 qv[4], kv[4];
#pragma unroll
        for (int i = 0; i < 4; ++i) qv[i] = *(const float4*)&Qs[(ty << 2) + i][d];
#pragma unroll
        for (int j = 0; j < 4; ++j) kv[j] = *(const float4*)&Ks[(tx << 2) + j][d];
#pragma unroll
        for (int i = 0; i < 4; ++i)
#pragma unroll
            for (int j = 0; j < 4; ++j)
                acc[i][j] += qv[i].x * kv[j].x + qv[i].y * kv[j].y +
                             qv[i].z * kv[j].z + qv[i].w * kv[j].w;
    }
#pragma unroll
    for (int i = 0; i < 4; ++i) {
        int m = m0 + (ty << 2) + i;
        float4 o;
        o.x = acc[i][0] * 0.125f; o.y = acc[i][1] * 0.125f;
        o.z = acc[i][2] * 0.125f; o.w = acc[i][3] * 0.125f;
        *(float4*)&logits[((size_t)(bh * L_SEQ + m) << 10) + n0 + (tx << 2)] = o;
    }
}

// ---------------- fused Sinkhorn pass ----------------
// Per block: 16 rows of one (b,h). Row update: r_new = r_prev + log(sum_j exp(x-c-r_prev))
// (all terms <= 1 by construction). Col partial: colacc_j += term_j / rowsum
// == exp(x - r_new - c). One exp per element, one read of logits per iteration.
__global__ __launch_bounds__(256) void sinkhorn_pass(
    const float* __restrict__ logits, float* __restrict__ r,
    const float* __restrict__ c, float* __restrict__ part)
{
    const int chunk = blockIdx.x;   // 0..63 (16 rows each)
    const int bh = blockIdx.y;      // 0..15
    const int t = threadIdx.x;
    const int w = t >> 6, lane = t & 63;
    __shared__ float wpart[4][1024];
    const float* cb = c + bh * L_SEQ;
    float4 c4[4];
#pragma unroll
    for (int p = 0; p < 4; ++p) c4[p] = *(const float4*)&cb[(p << 8) + (lane << 2)];
    float4 acc4[4] = {};
    const int i0 = chunk * 16 + w * 4;
#pragma unroll
    for (int rr = 0; rr < 4; ++rr) {
        const int i = i0 + rr;
        const float rp = r[bh * L_SEQ + i];
        const float* row = logits + (((size_t)(bh * L_SEQ + i)) << 10);
        float4 t4[4];
        float s = 0.0f;
#pragma unroll
        for (int p = 0; p < 4; ++p) {
            float4 x4 = *(const float4*)&row[(p << 8) + (lane << 2)];
            t4[p].x = __expf(x4.x - c4[p].x - rp);
            t4[p].y = __expf(x4.y - c4[p].y - rp);
            t4[p].z = __expf(x4.z - c4[p].z - rp);
            t4[p].w = __expf(x4.w - c4[p].w - rp);
            s += t4[p].x + t4[p].y + t4[p].z + t4[p].w;
        }
#pragma unroll
        for (int off = 32; off > 0; off >>= 1) s += __shfl_xor(s, off);
        if (lane == 0) r[bh * L_SEQ + i] = rp + __logf(s);
        const float inv = 1.0f / s;
#pragma unroll
        for (int p = 0; p < 4; ++p) {
            acc4[p].x += t4[p].x * inv; acc4[p].y += t4[p].y * inv;
            acc4[p].z += t4[p].z * inv; acc4[p].w += t4[p].w * inv;
        }
    }
#pragma unroll
    for (int p = 0; p < 4; ++p)
        *(float4*)&wpart[w][(p << 8) + (lane << 2)] = acc4[p];
    __syncthreads();
    float* dst = part + (((size_t)(bh * 64 + chunk)) << 10);
#pragma unroll
    for (int p = 0; p < 4; ++p) {
        int col = t + (p << 8);
        dst[col] = wpart[0][col] + wpart[1][col] + wpart[2][col] + wpart[3][col];
    }
}

// c_j += log(sum over 64 chunk-partials)
__global__ __launch_bounds__(256) void sinkhorn_merge(
    const float* __restrict__ part, float* __restrict__ c)
{
    const int g = blockIdx.x * 256 + threadIdx.x;  // 0..16383
    const int bh = g >> 10, j = g & 1023;
    const float* p = part + (((size_t)bh) << 16) + j;
    float s = 0.0f;
#pragma unroll 8
    for (int ch = 0; ch < 64; ++ch) s += p[(size_t)ch << 10];
    c[g] += __logf(s);
}

// ---------------- out_pre = exp(logits - r - c) @ v ----------------
__global__ __launch_bounds__(256) void attn_v(
    const float* __restrict__ logits, const float* __restrict__ r,
    const float* __restrict__ c, const float* __restrict__ v,
    float* __restrict__ out_pre)
{
    const int bh = blockIdx.y;
    const int m0 = blockIdx.x << 6;
    __shared__ float Es[64][36];
    __shared__ float Vs[32][68];
    const int t = threadIdx.x;
    const int tx = t & 15, ty = t >> 4;
    const int erow = t >> 2, ej4 = (t & 3) << 2;
    const float rp = r[bh * L_SEQ + m0 + erow];
    const size_t lrow_off = ((size_t)(bh * L_SEQ + m0 + erow)) << 10;
    const int vd4 = (t & 15) << 2, vj = t >> 4;
    float acc[4][4] = {};
    for (int j0 = 0; j0 < L_SEQ; j0 += 32) {
        __syncthreads();
#pragma unroll
        for (int ss = 0; ss < 32; ss += 16) {
            float4 xv = *(const float4*)&logits[lrow_off + j0 + ej4 + ss];
            float4 cc = *(const float4*)&c[bh * L_SEQ + j0 + ej4 + ss];
            float4 e;
            e.x = __expf(xv.x - rp - cc.x);
            e.y = __expf(xv.y - rp - cc.y);
            e.z = __expf(xv.z - rp - cc.z);
            e.w = __expf(xv.w - rp - cc.w);
            *(float4*)&Es[erow][ej4 + ss] = e;
        }
#pragma unroll
        for (int ss = 0; ss < 32; ss += 16) {
            *(float4*)&Vs[vj + ss][vd4] =
                *(const float4*)&v[(size_t)(bh * L_SEQ + j0 + vj + ss) * D_HEAD + vd4];
        }
        __syncthreads();
#pragma unroll
        for (int kk = 0; kk < 32; ++kk) {
            float a0 = Es[(ty << 2) + 0][kk];
            float a1 = Es[(ty << 2) + 1][kk];
            float a2 = Es[(ty << 2) + 2][kk];
            float a3 = Es[(ty << 2) + 3][kk];
            float4 b = *(const float4*)&Vs[kk][tx << 2];
            acc[0][0] += a0 * b.x; acc[0][1] += a0 * b.y; acc[0][2] += a0 * b.z; acc[0][3] += a0 * b.w;
            acc[1][0] += a1 * b.x; acc[1][1] += a1 * b.y; acc[1][2] += a1 * b.z; acc[1][3] += a1 * b.w;
            acc[2][0] += a2 * b.x; acc[2][1] += a2 * b.y; acc[2][2] += a2 * b.z; acc[2][3] += a2 * b.w;
            acc[3][0] += a3 * b.x; acc[3][1] += a3 * b.y; acc[3][2] += a3 * b.z; acc[3][3] += a3 * b.w;
        }
    }
    const int b = bh >> 3, h = bh & 7;
#pragma unroll
    for (int i = 0; i < 4; ++i) {
        int l = m0 + (ty << 2) + i;
        float4 o;
        o.x = acc[i][0]; o.y = acc[i][1]; o.z = acc[i][2]; o.w = acc[i][3];
        *(float4*)&out_pre[(size_t)(b * L_SEQ + l) * N_HD + (h << 6) + (tx << 2)] = o;
    }
}

extern "C" void kernel_launch(void* const* d_in, const int* in_sizes, int n_in,
                              void* d_out, int out_size, void* d_ws, size_t ws_size,
                              hipStream_t stream)
{
    const float* x  = (const float*)d_in[0];
    const float* Wq = (const float*)d_in[1];
    const float* bq = (const float*)d_in[2];
    const float* Wk = (const float*)d_in[3];
    const float* bk = (const float*)d_in[4];
    const float* Wv = (const float*)d_in[5];
    const float* bv = (const float*)d_in[6];
    const float* Wo = (const float*)d_in[7];
    const float* bo = (const float*)d_in[8];
    float* out = (float*)d_out;

    float* ws      = (float*)d_ws;
    float* q       = ws;                     // 1M floats
    float* k       = q + (1 << 20);          // 1M
    float* v       = k + (1 << 20);          // 1M
    float* logits  = v + (1 << 20);          // 16M
    float* r       = logits + (16 << 20);    // 16K
    float* c       = r + (16 << 10);         // 16K
    float* part    = c + (16 << 10);         // 1M
    float* out_pre = part + (1 << 20);       // 1M  (total ~84 MB)

    init_rc<<<dim3(64), 256, 0, stream>>>(r, c);
    gemm_qkv<<<dim3(8, 32, 3), 256, 0, stream>>>(x, Wq, bq, Wk, bk, Wv, bv, q, k, v);
    logits_qkT<<<dim3(16, 16, 16), 256, 0, stream>>>(q, k, logits);
    for (int it = 0; it < N_ITERS; ++it) {
        sinkhorn_pass<<<dim3(64, 16), 256, 0, stream>>>(logits, r, c, part);
        sinkhorn_merge<<<dim3(64), 256, 0, stream>>>(part, c);
    }
    attn_v<<<dim3(16, 16), 256, 0, stream>>>(logits, r, c, v, out_pre);
    gemm_out<<<dim3(16, 32), 256, 0, stream>>>(out_pre, Wo, bo, out);
}

// Round 2
// 467.467 us; speedup vs baseline: 1.4416x; 1.4416x over previous
//
#include <hip/hip_runtime.h>
#include <hip/hip_bf16.h>
#include <hip/hip_fp16.h>
#include <math.h>

#define L_SEQ 1024
#define D_HEAD 64
#define N_EMB 1024
#define N_HD 512
#define N_BH 16
#define N_ITERS 20
#define R_INIT 20.0f   // safe shift: exp(x - c - r) <= 1 on first pass

typedef short short8 __attribute__((ext_vector_type(8)));   // 8 bf16 = 4 VGPRs
typedef float floatx4 __attribute__((ext_vector_type(4)));  // MFMA acc

__device__ __forceinline__ unsigned short f2bf(float f) {
    unsigned int u = __float_as_uint(f);
    u += 0x7FFFu + ((u >> 16) & 1u);   // round-to-nearest-even
    return (unsigned short)(u >> 16);
}

// ---------------- init r/c ----------------
__global__ void init_rc(float* __restrict__ r, float* __restrict__ c) {
    int i = blockIdx.x * 256 + threadIdx.x;
    if (i < N_BH * L_SEQ) { r[i] = R_INIT; c[i] = 0.0f; }
}

// ---------------- prep: fp32 -> bf16 ----------------
__global__ __launch_bounds__(256) void convert_x(const float* __restrict__ x,
                                                 unsigned short* __restrict__ xb) {
    const int i = (blockIdx.x * 256 + threadIdx.x) << 4;  // 16 elems/thread
    unsigned short tmp[16];
#pragma unroll
    for (int p = 0; p < 4; ++p) {
        float4 f = *(const float4*)&x[i + (p << 2)];
        tmp[p * 4 + 0] = f2bf(f.x); tmp[p * 4 + 1] = f2bf(f.y);
        tmp[p * 4 + 2] = f2bf(f.z); tmp[p * 4 + 3] = f2bf(f.w);
    }
    *(uint4*)&xb[i]     = *(const uint4*)&tmp[0];
    *(uint4*)&xb[i + 8] = *(const uint4*)&tmp[8];
}

// W (1024 x 512) -> wT (512 x 1024) bf16, z selects q/k/v
__global__ __launch_bounds__(256) void transpose_w(
    const float* __restrict__ Wq, const float* __restrict__ Wk, const float* __restrict__ Wv,
    unsigned short* __restrict__ wqT, unsigned short* __restrict__ wkT,
    unsigned short* __restrict__ wvT)
{
    const int z = blockIdx.z;
    const float* Wsrc = (z == 0) ? Wq : (z == 1) ? Wk : Wv;
    unsigned short* wT = (z == 0) ? wqT : (z == 1) ? wkT : wvT;
    __shared__ float Tls[32][33];
    const int t = threadIdx.x;
    const int n0 = blockIdx.x << 5, k0 = blockIdx.y << 5;
    const int rl = t >> 5, cl = t & 31;
#pragma unroll
    for (int i = 0; i < 4; ++i)
        Tls[rl + (i << 3)][cl] = Wsrc[(size_t)(k0 + rl + (i << 3)) * N_HD + n0 + cl];
    __syncthreads();
#pragma unroll
    for (int i = 0; i < 4; ++i)
        wT[(size_t)(n0 + rl + (i << 3)) * N_EMB + k0 + cl] = f2bf(Tls[cl][rl + (i << 3)]);
}

// ---------------- bf16 MFMA QKV projection ----------------
// C(2048x512) = xb(2048x1024) @ wT(512x1024)^T ; z = 0/1/2 -> q/k/v
// q,k stored bf16 [bh][l][d]; v stored fp32 [bh][l][d]
__global__ __launch_bounds__(256) void mfma_qkv(
    const unsigned short* __restrict__ xb,
    const unsigned short* __restrict__ wqT, const unsigned short* __restrict__ wkT,
    const unsigned short* __restrict__ wvT,
    const float* __restrict__ bq, const float* __restrict__ bk, const float* __restrict__ bv,
    unsigned short* __restrict__ qb, unsigned short* __restrict__ kb, float* __restrict__ v)
{
    const int pz = blockIdx.z;
    const unsigned short* wT = (pz == 0) ? wqT : (pz == 1) ? wkT : wvT;
    const float* bias = (pz == 0) ? bq : (pz == 1) ? bk : bv;
    __shared__ __align__(16) unsigned short Als[128 * 40];  // pitch 40 ush (80B): 2-way banks
    __shared__ __align__(16) unsigned short Bls[128 * 40];
    const int t = threadIdx.x;
    const int m0 = blockIdx.y << 7, n0 = blockIdx.x << 7;
    const int w = t >> 6, lane = t & 63;
    const int quad = lane >> 4, l16 = lane & 15;
    const int wr = w >> 1, wc = w & 1;
    const int ra = t >> 2, ka = (t & 3) << 3;
    floatx4 acc[4][4] = {};
    for (int k0 = 0; k0 < N_EMB; k0 += 32) {
        uint4 a0 = *(const uint4*)&xb[(size_t)(m0 + ra) * N_EMB + k0 + ka];
        uint4 a1 = *(const uint4*)&xb[(size_t)(m0 + ra + 64) * N_EMB + k0 + ka];
        uint4 b0 = *(const uint4*)&wT[(size_t)(n0 + ra) * N_EMB + k0 + ka];
        uint4 b1 = *(const uint4*)&wT[(size_t)(n0 + ra + 64) * N_EMB + k0 + ka];
        __syncthreads();
        *(uint4*)&Als[ra * 40 + ka] = a0;
        *(uint4*)&Als[(ra + 64) * 40 + ka] = a1;
        *(uint4*)&Bls[ra * 40 + ka] = b0;
        *(uint4*)&Bls[(ra + 64) * 40 + ka] = b1;
        __syncthreads();
        short8 af[4], bf[4];
#pragma unroll
        for (int i = 0; i < 4; ++i)
            af[i] = *(const short8*)&Als[(wr * 64 + i * 16 + l16) * 40 + quad * 8];
#pragma unroll
        for (int j = 0; j < 4; ++j)
            bf[j] = *(const short8*)&Bls[(wc * 64 + j * 16 + l16) * 40 + quad * 8];
#pragma unroll
        for (int i = 0; i < 4; ++i)
#pragma unroll
            for (int j = 0; j < 4; ++j)
                acc[i][j] = __builtin_amdgcn_mfma_f32_16x16x32_bf16(af[i], bf[j], acc[i][j], 0, 0, 0);
    }
    float bje[4];
    int hh[4], dd[4];
#pragma unroll
    for (int j = 0; j < 4; ++j) {
        int gn = n0 + wc * 64 + j * 16 + l16;
        bje[j] = bias[gn];
        hh[j] = gn >> 6; dd[j] = gn & 63;
    }
    unsigned short* qk = (pz == 0) ? qb : kb;
#pragma unroll
    for (int i = 0; i < 4; ++i)
#pragma unroll
    for (int p = 0; p < 4; ++p) {
        int gm = m0 + wr * 64 + i * 16 + quad * 4 + p;
        int bb = gm >> 10, l = gm & 1023;
#pragma unroll
        for (int j = 0; j < 4; ++j) {
            float val = acc[i][j][p] + bje[j];
            size_t dst = ((size_t)((bb << 3) + hh[j]) * L_SEQ + l) * D_HEAD + dd[j];
            if (pz < 2) qk[dst] = f2bf(val);
            else        v[dst] = val;
        }
    }
}

// ---------------- bf16 MFMA logits = q @ k^T / 8 -> fp16 ----------------
__global__ __launch_bounds__(256) void mfma_logits(
    const unsigned short* __restrict__ qb, const unsigned short* __restrict__ kb,
    __half* __restrict__ logh)
{
    const int bh = blockIdx.z;
    const int m0 = blockIdx.y << 7, n0 = blockIdx.x << 7;
    __shared__ __align__(16) unsigned short Qls[128 * 72];  // pitch 72 ush (144B)
    __shared__ __align__(16) unsigned short Kls[128 * 72];
    const int t = threadIdx.x;
    const int w = t >> 6, lane = t & 63;
    const int quad = lane >> 4, l16 = lane & 15;
    const int wr = w >> 1, wc = w & 1;
    const size_t base = (size_t)bh << 10;
#pragma unroll
    for (int i = 0; i < 4; ++i) {
        int ch = t + (i << 8);
        int row = ch >> 3, ko = (ch & 7) << 3;
        *(uint4*)&Qls[row * 72 + ko] = *(const uint4*)&qb[(base + m0 + row) * D_HEAD + ko];
        *(uint4*)&Kls[row * 72 + ko] = *(const uint4*)&kb[(base + n0 + row) * D_HEAD + ko];
    }
    __syncthreads();
    floatx4 acc[4][4] = {};
#pragma unroll
    for (int kk = 0; kk < 64; kk += 32) {
        short8 af[4], bf[4];
#pragma unroll
        for (int i = 0; i < 4; ++i)
            af[i] = *(const short8*)&Qls[(wr * 64 + i * 16 + l16) * 72 + kk + quad * 8];
#pragma unroll
        for (int j = 0; j < 4; ++j)
            bf[j] = *(const short8*)&Kls[(wc * 64 + j * 16 + l16) * 72 + kk + quad * 8];
#pragma unroll
        for (int i = 0; i < 4; ++i)
#pragma unroll
            for (int j = 0; j < 4; ++j)
                acc[i][j] = __builtin_amdgcn_mfma_f32_16x16x32_bf16(af[i], bf[j], acc[i][j], 0, 0, 0);
    }
#pragma unroll
    for (int i = 0; i < 4; ++i)
#pragma unroll
    for (int p = 0; p < 4; ++p) {
        int gm = m0 + wr * 64 + i * 16 + quad * 4 + p;
#pragma unroll
        for (int j = 0; j < 4; ++j) {
            int gn = n0 + wc * 64 + j * 16 + l16;
            logh[((size_t)bh << 20) + ((size_t)gm << 10) + gn] = __float2half(acc[i][j][p] * 0.125f);
        }
    }
}

// ---------------- fused Sinkhorn pass (fp16 logits) ----------------
__global__ __launch_bounds__(256) void sinkhorn_pass(
    const __half* __restrict__ logh, float* __restrict__ r,
    const float* __restrict__ c, float* __restrict__ part)
{
    const int chunk = blockIdx.x;   // 0..63 (16 rows each)
    const int bh = blockIdx.y;      // 0..15
    const int t = threadIdx.x;
    const int w = t >> 6, lane = t & 63;
    __shared__ float wpart[4][1024];
    const float* cb = c + (bh << 10);
    float cc[2][8];
#pragma unroll
    for (int p = 0; p < 2; ++p) {
        float4 c0 = *(const float4*)&cb[(p << 9) + (lane << 3)];
        float4 c1 = *(const float4*)&cb[(p << 9) + (lane << 3) + 4];
        cc[p][0] = c0.x; cc[p][1] = c0.y; cc[p][2] = c0.z; cc[p][3] = c0.w;
        cc[p][4] = c1.x; cc[p][5] = c1.y; cc[p][6] = c1.z; cc[p][7] = c1.w;
    }
    float acc[2][8] = {};
    const int i0 = (chunk << 4) + (w << 2);
#pragma unroll
    for (int rr = 0; rr < 4; ++rr) {
        const int i = i0 + rr;
        const float rp = r[(bh << 10) + i];
        const __half* row = logh + ((size_t)((bh << 10) + i) << 10);
        float tt[2][8];
        float s = 0.0f;
#pragma unroll
        for (int p = 0; p < 2; ++p) {
            uint4 hx = *(const uint4*)(row + (p << 9) + (lane << 3));  // 8 halfs
            const __half* hp = (const __half*)&hx;
#pragma unroll
            for (int j = 0; j < 8; ++j) {
                tt[p][j] = __expf(__half2float(hp[j]) - cc[p][j] - rp);
                s += tt[p][j];
            }
        }
#pragma unroll
        for (int off = 32; off > 0; off >>= 1) s += __shfl_xor(s, off);
        if (lane == 0) r[(bh << 10) + i] = rp + __logf(s);
        const float inv = 1.0f / s;
#pragma unroll
        for (int p = 0; p < 2; ++p)
#pragma unroll
            for (int j = 0; j < 8; ++j) acc[p][j] += tt[p][j] * inv;
    }
#pragma unroll
    for (int p = 0; p < 2; ++p) {
        *(float4*)&wpart[w][(p << 9) + (lane << 3)]     = make_float4(acc[p][0], acc[p][1], acc[p][2], acc[p][3]);
        *(float4*)&wpart[w][(p << 9) + (lane << 3) + 4] = make_float4(acc[p][4], acc[p][5], acc[p][6], acc[p][7]);
    }
    __syncthreads();
    float* dst = part + ((size_t)((bh << 6) + chunk) << 10);
#pragma unroll
    for (int p = 0; p < 4; ++p) {
        int col = t + (p << 8);
        dst[col] = wpart[0][col] + wpart[1][col] + wpart[2][col] + wpart[3][col];
    }
}

// c_j += log(sum over 64 chunk-partials)
__global__ __launch_bounds__(256) void sinkhorn_merge(
    const float* __restrict__ part, float* __restrict__ c)
{
    const int g = blockIdx.x * 256 + threadIdx.x;  // 0..16383
    const int bh = g >> 10, j = g & 1023;
    const float* p = part + (((size_t)bh) << 16) + j;
    float s = 0.0f;
#pragma unroll 8
    for (int ch = 0; ch < 64; ++ch) s += p[(size_t)ch << 10];
    c[g] += __logf(s);
}

// ---------------- out_pre = exp(logits - r - c) @ v (fp16 logits, fp32 v) ----------------
__global__ __launch_bounds__(256) void attn_v(
    const __half* __restrict__ logh, const float* __restrict__ r,
    const float* __restrict__ c, const float* __restrict__ v,
    float* __restrict__ out_pre)
{
    const int bh = blockIdx.y;
    const int m0 = blockIdx.x << 6;
    __shared__ float Es[64][36];
    __shared__ float Vs[32][68];
    const int t = threadIdx.x;
    const int tx = t & 15, ty = t >> 4;
    const int erow = t >> 2, ej4 = (t & 3) << 2;
    const float rp = r[(bh << 10) + m0 + erow];
    const __half* lrow = logh + ((size_t)((bh << 10) + m0 + erow) << 10);
    const int vd4 = (t & 15) << 2, vj = t >> 4;
    float acc[4][4] = {};
    for (int j0 = 0; j0 < L_SEQ; j0 += 32) {
        __syncthreads();
#pragma unroll
        for (int ss = 0; ss < 32; ss += 16) {
            ushort4 hx = *(const ushort4*)(lrow + j0 + ej4 + ss);
            const __half* hp = (const __half*)&hx;
            float4 cc = *(const float4*)&c[(bh << 10) + j0 + ej4 + ss];
            float4 e;
            e.x = __expf(__half2float(hp[0]) - rp - cc.x);
            e.y = __expf(__half2float(hp[1]) - rp - cc.y);
            e.z = __expf(__half2float(hp[2]) - rp - cc.z);
            e.w = __expf(__half2float(hp[3]) - rp - cc.w);
            *(float4*)&Es[erow][ej4 + ss] = e;
        }
#pragma unroll
        for (int ss = 0; ss < 32; ss += 16) {
            *(float4*)&Vs[vj + ss][vd4] =
                *(const float4*)&v[(size_t)((bh << 10) + j0 + vj + ss) * D_HEAD + vd4];
        }
        __syncthreads();
#pragma unroll
        for (int kk = 0; kk < 32; ++kk) {
            float a0 = Es[(ty << 2) + 0][kk];
            float a1 = Es[(ty << 2) + 1][kk];
            float a2 = Es[(ty << 2) + 2][kk];
            float a3 = Es[(ty << 2) + 3][kk];
            float4 b = *(const float4*)&Vs[kk][tx << 2];
            acc[0][0] += a0 * b.x; acc[0][1] += a0 * b.y; acc[0][2] += a0 * b.z; acc[0][3] += a0 * b.w;
            acc[1][0] += a1 * b.x; acc[1][1] += a1 * b.y; acc[1][2] += a1 * b.z; acc[1][3] += a1 * b.w;
            acc[2][0] += a2 * b.x; acc[2][1] += a2 * b.y; acc[2][2] += a2 * b.z; acc[2][3] += a2 * b.w;
            acc[3][0] += a3 * b.x; acc[3][1] += a3 * b.y; acc[3][2] += a3 * b.z; acc[3][3] += a3 * b.w;
        }
    }
    const int b = bh >> 3, h = bh & 7;
#pragma unroll
    for (int i = 0; i < 4; ++i) {
        int l = m0 + (ty << 2) + i;
        float4 o;
        o.x = acc[i][0]; o.y = acc[i][1]; o.z = acc[i][2]; o.w = acc[i][3];
        *(float4*)&out_pre[(size_t)(b * L_SEQ + l) * N_HD + (h << 6) + (tx << 2)] = o;
    }
}

// ---------------- fp32 output GEMM (unchanged) ----------------
__device__ __forceinline__ void gemm_body(
    const float* __restrict__ A, const float* __restrict__ B,
    const float* __restrict__ bias, float* __restrict__ C,
    int N, int K)
{
    __shared__ float AsT[16][68];
    __shared__ float Bs[16][68];
    const int t = threadIdx.x;
    const int tx = t & 15, ty = t >> 4;
    const int m0 = blockIdx.y << 6, n0 = blockIdx.x << 6;
    const int arow = t >> 2, ak = (t & 3) << 2;
    const int brow = t >> 4, bc = (t & 15) << 2;
    float acc[4][4] = {};
    for (int k0 = 0; k0 < K; k0 += 16) {
        float4 av = *(const float4*)&A[(size_t)(m0 + arow) * K + k0 + ak];
        float4 bv = *(const float4*)&B[(size_t)(k0 + brow) * N + n0 + bc];
        __syncthreads();
        AsT[ak + 0][arow] = av.x;
        AsT[ak + 1][arow] = av.y;
        AsT[ak + 2][arow] = av.z;
        AsT[ak + 3][arow] = av.w;
        *(float4*)&Bs[brow][bc] = bv;
        __syncthreads();
#pragma unroll
        for (int kk = 0; kk < 16; ++kk) {
            float4 a = *(const float4*)&AsT[kk][ty << 2];
            float4 b = *(const float4*)&Bs[kk][tx << 2];
            acc[0][0] += a.x * b.x; acc[0][1] += a.x * b.y; acc[0][2] += a.x * b.z; acc[0][3] += a.x * b.w;
            acc[1][0] += a.y * b.x; acc[1][1] += a.y * b.y; acc[1][2] += a.y * b.z; acc[1][3] += a.y * b.w;
            acc[2][0] += a.z * b.x; acc[2][1] += a.z * b.y; acc[2][2] += a.z * b.z; acc[2][3] += a.z * b.w;
            acc[3][0] += a.w * b.x; acc[3][1] += a.w * b.y; acc[3][2] += a.w * b.z; acc[3][3] += a.w * b.w;
        }
    }
    float4 bi = *(const float4*)&bias[n0 + (tx << 2)];
#pragma unroll
    for (int i = 0; i < 4; ++i) {
        int m = m0 + (ty << 2) + i;
        float4 o;
        o.x = acc[i][0] + bi.x; o.y = acc[i][1] + bi.y;
        o.z = acc[i][2] + bi.z; o.w = acc[i][3] + bi.w;
        *(float4*)&C[(size_t)m * N + n0 + (tx << 2)] = o;
    }
}

__global__ __launch_bounds__(256) void gemm_out(
    const float* __restrict__ A, const float* __restrict__ Wo,
    const float* __restrict__ bo, float* __restrict__ C)
{
    gemm_body(A, Wo, bo, C, N_EMB, N_HD);
}

extern "C" void kernel_launch(void* const* d_in, const int* in_sizes, int n_in,
                              void* d_out, int out_size, void* d_ws, size_t ws_size,
                              hipStream_t stream)
{
    const float* x  = (const float*)d_in[0];
    const float* Wq = (const float*)d_in[1];
    const float* bq = (const float*)d_in[2];
    const float* Wk = (const float*)d_in[3];
    const float* bk = (const float*)d_in[4];
    const float* Wv = (const float*)d_in[5];
    const float* bv = (const float*)d_in[6];
    const float* Wo = (const float*)d_in[7];
    const float* bo = (const float*)d_in[8];
    float* out = (float*)d_out;

    char* W = (char*)d_ws;
    unsigned short* xb  = (unsigned short*)(W);                    // 4 MB
    unsigned short* wqT = (unsigned short*)(W + (4ll  << 20));     // 1 MB
    unsigned short* wkT = (unsigned short*)(W + (5ll  << 20));     // 1 MB
    unsigned short* wvT = (unsigned short*)(W + (6ll  << 20));     // 1 MB
    unsigned short* qb  = (unsigned short*)(W + (7ll  << 20));     // 2 MB
    unsigned short* kb  = (unsigned short*)(W + (9ll  << 20));     // 2 MB
    float* v            = (float*)(W + (11ll << 20));              // 4 MB
    __half* logh        = (__half*)(W + (15ll << 20));             // 32 MB
    float* r            = (float*)(W + (47ll << 20));              // 64 KB
    float* cvec         = (float*)(W + (47ll << 20) + 65536);      // 64 KB
    float* part         = (float*)(W + (48ll << 20));              // 4 MB
    float* out_pre      = (float*)(W + (52ll << 20));              // 4 MB

    convert_x<<<512, 256, 0, stream>>>(x, xb);
    transpose_w<<<dim3(16, 32, 3), 256, 0, stream>>>(Wq, Wk, Wv, wqT, wkT, wvT);
    init_rc<<<64, 256, 0, stream>>>(r, cvec);
    mfma_qkv<<<dim3(4, 16, 3), 256, 0, stream>>>(xb, wqT, wkT, wvT, bq, bk, bv, qb, kb, v);
    mfma_logits<<<dim3(8, 8, 16), 256, 0, stream>>>(qb, kb, logh);
    for (int it = 0; it < N_ITERS; ++it) {
        sinkhorn_pass<<<dim3(64, 16), 256, 0, stream>>>(logh, r, cvec, part);
        sinkhorn_merge<<<64, 256, 0, stream>>>(part, cvec);
    }
    attn_v<<<dim3(16, 16), 256, 0, stream>>>(logh, r, cvec, v, out_pre);
    gemm_out<<<dim3(16, 32), 256, 0, stream>>>(out_pre, Wo, bo, out);
}

// Round 3
// 394.636 us; speedup vs baseline: 1.7076x; 1.1846x over previous
//
#include <hip/hip_runtime.h>
#include <hip/hip_fp16.h>
#include <math.h>

#define L_SEQ 1024
#define N_EMB 1024
#define N_HD 512
#define N_ITERS 20

typedef short short8 __attribute__((ext_vector_type(8)));   // 8 bf16 = 4 VGPRs
typedef float floatx4 __attribute__((ext_vector_type(4)));  // MFMA acc

__device__ __forceinline__ unsigned short f2bf(float f) {
    unsigned int u = __float_as_uint(f);
    u += 0x7FFFu + ((u >> 16) & 1u);   // round-to-nearest-even
    return (unsigned short)(u >> 16);
}

// ---------------- init u/v scale vectors ----------------
__global__ void init_uv(float* __restrict__ u, float* __restrict__ v) {
    int i = blockIdx.x * 256 + threadIdx.x;
    if (i < 16384) { u[i] = 0.0f; v[i] = 1.0f; }
}

// ---------------- prep: fp32 -> bf16 ----------------
__global__ __launch_bounds__(256) void convert_x(const float* __restrict__ x,
                                                 unsigned short* __restrict__ xb) {
    const int i = (blockIdx.x * 256 + threadIdx.x) << 4;  // 16 elems/thread
    unsigned short tmp[16];
#pragma unroll
    for (int p = 0; p < 4; ++p) {
        float4 f = *(const float4*)&x[i + (p << 2)];
        tmp[p * 4 + 0] = f2bf(f.x); tmp[p * 4 + 1] = f2bf(f.y);
        tmp[p * 4 + 2] = f2bf(f.z); tmp[p * 4 + 3] = f2bf(f.w);
    }
    *(uint4*)&xb[i]     = *(const uint4*)&tmp[0];
    *(uint4*)&xb[i + 8] = *(const uint4*)&tmp[8];
}

// Transpose all 4 weights to [n][k] bf16. z: 0..2 = Wq/Wk/Wv (1024x512), 3 = Wo (512x1024)
__global__ __launch_bounds__(256) void transpose_all(
    const float* __restrict__ Wq, const float* __restrict__ Wk,
    const float* __restrict__ Wv, const float* __restrict__ Wo,
    unsigned short* __restrict__ wqT, unsigned short* __restrict__ wkT,
    unsigned short* __restrict__ wvT, unsigned short* __restrict__ woT)
{
    const int z = blockIdx.z;
    const float* S; unsigned short* D; int rows, cols;
    if (z == 0)      { S = Wq; D = wqT; rows = 1024; cols = 512; }
    else if (z == 1) { S = Wk; D = wkT; rows = 1024; cols = 512; }
    else if (z == 2) { S = Wv; D = wvT; rows = 1024; cols = 512; }
    else             { S = Wo; D = woT; rows = 512;  cols = 1024; }
    const int n0 = blockIdx.x << 5, k0 = blockIdx.y << 5;
    if (n0 >= cols || k0 >= rows) return;
    __shared__ float Tls[32][33];
    const int t = threadIdx.x;
    const int rl = t >> 5, cl = t & 31;
#pragma unroll
    for (int i = 0; i < 4; ++i)
        Tls[rl + (i << 3)][cl] = S[(size_t)(k0 + rl + (i << 3)) * cols + n0 + cl];
    __syncthreads();
#pragma unroll
    for (int i = 0; i < 4; ++i)
        D[(size_t)(n0 + rl + (i << 3)) * rows + k0 + cl] = f2bf(Tls[cl][rl + (i << 3)]);
}

// ---------------- bf16 MFMA QKV projection ----------------
// q,k bf16 [bh][l][d]; v bf16 TRANSPOSED [bh][d][l]
__global__ __launch_bounds__(256) void mfma_qkv(
    const unsigned short* __restrict__ xb,
    const unsigned short* __restrict__ wqT, const unsigned short* __restrict__ wkT,
    const unsigned short* __restrict__ wvT,
    const float* __restrict__ bq, const float* __restrict__ bk, const float* __restrict__ bv,
    unsigned short* __restrict__ qb, unsigned short* __restrict__ kb,
    unsigned short* __restrict__ vt)
{
    const int pz = blockIdx.z;
    const unsigned short* wT = (pz == 0) ? wqT : (pz == 1) ? wkT : wvT;
    const float* bias = (pz == 0) ? bq : (pz == 1) ? bk : bv;
    __shared__ __align__(16) unsigned short Als[128 * 40];
    __shared__ __align__(16) unsigned short Bls[128 * 40];
    const int t = threadIdx.x;
    const int m0 = blockIdx.y << 7, n0 = blockIdx.x << 7;
    const int w = t >> 6, lane = t & 63;
    const int quad = lane >> 4, l16 = lane & 15;
    const int wr = w >> 1, wc = w & 1;
    const int ra = t >> 2, ka = (t & 3) << 3;
    floatx4 acc[4][4] = {};
    for (int k0 = 0; k0 < N_EMB; k0 += 32) {
        uint4 a0 = *(const uint4*)&xb[(size_t)(m0 + ra) * N_EMB + k0 + ka];
        uint4 a1 = *(const uint4*)&xb[(size_t)(m0 + ra + 64) * N_EMB + k0 + ka];
        uint4 b0 = *(const uint4*)&wT[(size_t)(n0 + ra) * N_EMB + k0 + ka];
        uint4 b1 = *(const uint4*)&wT[(size_t)(n0 + ra + 64) * N_EMB + k0 + ka];
        __syncthreads();
        *(uint4*)&Als[ra * 40 + ka] = a0;
        *(uint4*)&Als[(ra + 64) * 40 + ka] = a1;
        *(uint4*)&Bls[ra * 40 + ka] = b0;
        *(uint4*)&Bls[(ra + 64) * 40 + ka] = b1;
        __syncthreads();
        short8 af[4], bf[4];
#pragma unroll
        for (int i = 0; i < 4; ++i)
            af[i] = *(const short8*)&Als[(wr * 64 + i * 16 + l16) * 40 + quad * 8];
#pragma unroll
        for (int j = 0; j < 4; ++j)
            bf[j] = *(const short8*)&Bls[(wc * 64 + j * 16 + l16) * 40 + quad * 8];
#pragma unroll
        for (int i = 0; i < 4; ++i)
#pragma unroll
            for (int j = 0; j < 4; ++j)
                acc[i][j] = __builtin_amdgcn_mfma_f32_16x16x32_bf16(af[i], bf[j], acc[i][j], 0, 0, 0);
    }
    float bje[4];
    int hh[4], dd[4];
#pragma unroll
    for (int j = 0; j < 4; ++j) {
        int gn = n0 + wc * 64 + j * 16 + l16;
        bje[j] = bias[gn];
        hh[j] = gn >> 6; dd[j] = gn & 63;
    }
    unsigned short* qk = (pz == 0) ? qb : kb;
#pragma unroll
    for (int i = 0; i < 4; ++i)
#pragma unroll
    for (int p = 0; p < 4; ++p) {
        int gm = m0 + wr * 64 + i * 16 + quad * 4 + p;
        int bb = gm >> 10, l = gm & 1023;
#pragma unroll
        for (int j = 0; j < 4; ++j) {
            float val = acc[i][j][p] + bje[j];
            int bh = (bb << 3) + hh[j];
            if (pz < 2) qk[((size_t)bh * L_SEQ + l) * 64 + dd[j]] = f2bf(val);
            else        vt[((size_t)bh << 16) + ((size_t)dd[j] << 10) + l] = f2bf(val);
        }
    }
}

// ---------------- E = exp(q @ k^T / 8) -> fp16 ----------------
__global__ __launch_bounds__(256) void mfma_logits(
    const unsigned short* __restrict__ qb, const unsigned short* __restrict__ kb,
    __half* __restrict__ E)
{
    const int bh = blockIdx.z;
    const int m0 = blockIdx.y << 7, n0 = blockIdx.x << 7;
    __shared__ __align__(16) unsigned short Qls[128 * 72];
    __shared__ __align__(16) unsigned short Kls[128 * 72];
    const int t = threadIdx.x;
    const int w = t >> 6, lane = t & 63;
    const int quad = lane >> 4, l16 = lane & 15;
    const int wr = w >> 1, wc = w & 1;
    const size_t base = (size_t)bh << 10;
#pragma unroll
    for (int i = 0; i < 4; ++i) {
        int ch = t + (i << 8);
        int row = ch >> 3, ko = (ch & 7) << 3;
        *(uint4*)&Qls[row * 72 + ko] = *(const uint4*)&qb[(base + m0 + row) * 64 + ko];
        *(uint4*)&Kls[row * 72 + ko] = *(const uint4*)&kb[(base + n0 + row) * 64 + ko];
    }
    __syncthreads();
    floatx4 acc[4][4] = {};
#pragma unroll
    for (int kk = 0; kk < 64; kk += 32) {
        short8 af[4], bf[4];
#pragma unroll
        for (int i = 0; i < 4; ++i)
            af[i] = *(const short8*)&Qls[(wr * 64 + i * 16 + l16) * 72 + kk + quad * 8];
#pragma unroll
        for (int j = 0; j < 4; ++j)
            bf[j] = *(const short8*)&Kls[(wc * 64 + j * 16 + l16) * 72 + kk + quad * 8];
#pragma unroll
        for (int i = 0; i < 4; ++i)
#pragma unroll
            for (int j = 0; j < 4; ++j)
                acc[i][j] = __builtin_amdgcn_mfma_f32_16x16x32_bf16(af[i], bf[j], acc[i][j], 0, 0, 0);
    }
#pragma unroll
    for (int i = 0; i < 4; ++i)
#pragma unroll
    for (int p = 0; p < 4; ++p) {
        int gm = m0 + wr * 64 + i * 16 + quad * 4 + p;
#pragma unroll
        for (int j = 0; j < 4; ++j) {
            int gn = n0 + wc * 64 + j * 16 + l16;
            E[((size_t)bh << 20) + ((size_t)gm << 10) + gn] =
                __float2half(__expf(acc[i][j][p] * 0.125f));
        }
    }
}

// ---------------- multiplicative Sinkhorn pass ----------------
// u_i = 1/sum_j(E_ij * v_j); col partials part_j = sum_rows(E_ij * u_i)
__global__ __launch_bounds__(256) void sinkhorn_pass(
    const __half* __restrict__ E, float* __restrict__ u,
    const float* __restrict__ v, float* __restrict__ part)
{
    const int chunk = blockIdx.x;   // 0..63 (16 rows each)
    const int bh = blockIdx.y;      // 0..15
    const int t = threadIdx.x;
    const int w = t >> 6, lane = t & 63;
    __shared__ float wpart[4][1024];
    const float* vb = v + (bh << 10);
    float vv[16];
#pragma unroll
    for (int p = 0; p < 2; ++p) {
        float4 a = *(const float4*)&vb[(p << 9) + (lane << 3)];
        float4 c = *(const float4*)&vb[(p << 9) + (lane << 3) + 4];
        vv[p * 8 + 0] = a.x; vv[p * 8 + 1] = a.y; vv[p * 8 + 2] = a.z; vv[p * 8 + 3] = a.w;
        vv[p * 8 + 4] = c.x; vv[p * 8 + 5] = c.y; vv[p * 8 + 6] = c.z; vv[p * 8 + 7] = c.w;
    }
    float acc[16] = {};
    const int i0 = (chunk << 4) + (w << 2);
#pragma unroll
    for (int rr = 0; rr < 4; ++rr) {
        const int i = i0 + rr;
        const __half* row = E + (((size_t)(bh << 10) + i) << 10);
        float e[16];
        float s = 0.0f;
#pragma unroll
        for (int p = 0; p < 2; ++p) {
            uint4 hx = *(const uint4*)(row + (p << 9) + (lane << 3));
            const __half* hp = (const __half*)&hx;
#pragma unroll
            for (int jj = 0; jj < 8; ++jj) {
                e[p * 8 + jj] = __half2float(hp[jj]);
                s += e[p * 8 + jj] * vv[p * 8 + jj];
            }
        }
#pragma unroll
        for (int off = 32; off > 0; off >>= 1) s += __shfl_xor(s, off);
        const float ui = 1.0f / s;
        if (lane == 0) u[(bh << 10) + i] = ui;
#pragma unroll
        for (int jj = 0; jj < 16; ++jj) acc[jj] += e[jj] * ui;
    }
#pragma unroll
    for (int p = 0; p < 2; ++p) {
        *(float4*)&wpart[w][(p << 9) + (lane << 3)] =
            make_float4(acc[p * 8 + 0], acc[p * 8 + 1], acc[p * 8 + 2], acc[p * 8 + 3]);
        *(float4*)&wpart[w][(p << 9) + (lane << 3) + 4] =
            make_float4(acc[p * 8 + 4], acc[p * 8 + 5], acc[p * 8 + 6], acc[p * 8 + 7]);
    }
    __syncthreads();
    float* dst = part + ((size_t)((bh << 6) + chunk) << 10);
#pragma unroll
    for (int p = 0; p < 4; ++p) {
        int col = t + (p << 8);
        dst[col] = wpart[0][col] + wpart[1][col] + wpart[2][col] + wpart[3][col];
    }
}

// v_j = 1 / sum over 64 chunk-partials
__global__ __launch_bounds__(256) void sinkhorn_merge(
    const float* __restrict__ part, float* __restrict__ v)
{
    const int g = blockIdx.x * 256 + threadIdx.x;  // 0..16383
    const int bh = g >> 10, j = g & 1023;
    const float* p = part + ((size_t)bh << 16) + j;
    float s = 0.0f;
#pragma unroll 8
    for (int ch = 0; ch < 64; ++ch) s += p[(size_t)ch << 10];
    v[g] = 1.0f / s;
}

// ---------------- out_pre = (u * E * v) @ V via bf16 MFMA ----------------
__global__ __launch_bounds__(256) void attn_mfma(
    const __half* __restrict__ E, const float* __restrict__ u,
    const float* __restrict__ v, const unsigned short* __restrict__ vt,
    unsigned short* __restrict__ out_pre)
{
    const int bh = blockIdx.y;
    const int m0 = blockIdx.x << 6;
    const int b = bh >> 3, h = bh & 7;
    __shared__ __align__(16) unsigned short Pls[64 * 72];
    __shared__ __align__(16) unsigned short Vls[64 * 72];
    const int t = threadIdx.x;
    const int w = t >> 6, lane = t & 63;
    const int quad = lane >> 4, l16 = lane & 15;
    floatx4 acc[4] = {};
    for (int j0 = 0; j0 < L_SEQ; j0 += 64) {
        __syncthreads();
#pragma unroll
        for (int p = 0; p < 2; ++p) {
            int cidx = t + (p << 8);
            int row = cidx >> 3, c8 = (cidx & 7) << 3;
            uint4 hx = *(const uint4*)&E[(((size_t)(bh << 10) + m0 + row) << 10) + j0 + c8];
            const __half* hp = (const __half*)&hx;
            float ur = u[(bh << 10) + m0 + row];
            float4 v0 = *(const float4*)&v[(bh << 10) + j0 + c8];
            float4 v1 = *(const float4*)&v[(bh << 10) + j0 + c8 + 4];
            unsigned short pk[8];
            pk[0] = f2bf(__half2float(hp[0]) * ur * v0.x);
            pk[1] = f2bf(__half2float(hp[1]) * ur * v0.y);
            pk[2] = f2bf(__half2float(hp[2]) * ur * v0.z);
            pk[3] = f2bf(__half2float(hp[3]) * ur * v0.w);
            pk[4] = f2bf(__half2float(hp[4]) * ur * v1.x);
            pk[5] = f2bf(__half2float(hp[5]) * ur * v1.y);
            pk[6] = f2bf(__half2float(hp[6]) * ur * v1.z);
            pk[7] = f2bf(__half2float(hp[7]) * ur * v1.w);
            *(uint4*)&Pls[row * 72 + c8] = *(const uint4*)pk;
            *(uint4*)&Vls[row * 72 + c8] =
                *(const uint4*)&vt[((size_t)bh << 16) + ((size_t)row << 10) + j0 + c8];
        }
        __syncthreads();
#pragma unroll
        for (int kk = 0; kk < 64; kk += 32) {
            short8 af = *(const short8*)&Pls[(w * 16 + l16) * 72 + kk + quad * 8];
#pragma unroll
            for (int j = 0; j < 4; ++j) {
                short8 bfv = *(const short8*)&Vls[(j * 16 + l16) * 72 + kk + quad * 8];
                acc[j] = __builtin_amdgcn_mfma_f32_16x16x32_bf16(af, bfv, acc[j], 0, 0, 0);
            }
        }
    }
#pragma unroll
    for (int j = 0; j < 4; ++j)
#pragma unroll
    for (int p = 0; p < 4; ++p) {
        int l = m0 + w * 16 + quad * 4 + p;
        int d = (j << 4) + l16;
        out_pre[((size_t)((b << 10) + l)) * N_HD + (h << 6) + d] = f2bf(acc[j][p]);
    }
}

// ---------------- out = out_pre(bf16) @ Wo + bo via MFMA ----------------
__global__ __launch_bounds__(256) void mfma_out(
    const unsigned short* __restrict__ A,   // 2048 x 512 bf16
    const unsigned short* __restrict__ BT,  // woT: 1024 x 512 bf16
    const float* __restrict__ bo, float* __restrict__ C)
{
    __shared__ __align__(16) unsigned short Als[128 * 40];
    __shared__ __align__(16) unsigned short Bls[128 * 40];
    const int t = threadIdx.x;
    const int m0 = blockIdx.y << 7, n0 = blockIdx.x << 7;
    const int w = t >> 6, lane = t & 63;
    const int quad = lane >> 4, l16 = lane & 15;
    const int wr = w >> 1, wc = w & 1;
    const int ra = t >> 2, ka = (t & 3) << 3;
    floatx4 acc[4][4] = {};
    for (int k0 = 0; k0 < N_HD; k0 += 32) {
        uint4 a0 = *(const uint4*)&A[(size_t)(m0 + ra) * N_HD + k0 + ka];
        uint4 a1 = *(const uint4*)&A[(size_t)(m0 + ra + 64) * N_HD + k0 + ka];
        uint4 b0 = *(const uint4*)&BT[(size_t)(n0 + ra) * N_HD + k0 + ka];
        uint4 b1 = *(const uint4*)&BT[(size_t)(n0 + ra + 64) * N_HD + k0 + ka];
        __syncthreads();
        *(uint4*)&Als[ra * 40 + ka] = a0;
        *(uint4*)&Als[(ra + 64) * 40 + ka] = a1;
        *(uint4*)&Bls[ra * 40 + ka] = b0;
        *(uint4*)&Bls[(ra + 64) * 40 + ka] = b1;
        __syncthreads();
        short8 af[4], bf[4];
#pragma unroll
        for (int i = 0; i < 4; ++i)
            af[i] = *(const short8*)&Als[(wr * 64 + i * 16 + l16) * 40 + quad * 8];
#pragma unroll
        for (int j = 0; j < 4; ++j)
            bf[j] = *(const short8*)&Bls[(wc * 64 + j * 16 + l16) * 40 + quad * 8];
#pragma unroll
        for (int i = 0; i < 4; ++i)
#pragma unroll
            for (int j = 0; j < 4; ++j)
                acc[i][j] = __builtin_amdgcn_mfma_f32_16x16x32_bf16(af[i], bf[j], acc[i][j], 0, 0, 0);
    }
    float bje[4];
    int nn[4];
#pragma unroll
    for (int j = 0; j < 4; ++j) {
        nn[j] = n0 + wc * 64 + j * 16 + l16;
        bje[j] = bo[nn[j]];
    }
#pragma unroll
    for (int i = 0; i < 4; ++i)
#pragma unroll
    for (int p = 0; p < 4; ++p) {
        int m = m0 + wr * 64 + i * 16 + quad * 4 + p;
#pragma unroll
        for (int j = 0; j < 4; ++j)
            C[(size_t)m * N_EMB + nn[j]] = acc[i][j][p] + bje[j];
    }
}

extern "C" void kernel_launch(void* const* d_in, const int* in_sizes, int n_in,
                              void* d_out, int out_size, void* d_ws, size_t ws_size,
                              hipStream_t stream)
{
    const float* x  = (const float*)d_in[0];
    const float* Wq = (const float*)d_in[1];
    const float* bq = (const float*)d_in[2];
    const float* Wk = (const float*)d_in[3];
    const float* bk = (const float*)d_in[4];
    const float* Wv = (const float*)d_in[5];
    const float* bv = (const float*)d_in[6];
    const float* Wo = (const float*)d_in[7];
    const float* bo = (const float*)d_in[8];
    float* out = (float*)d_out;

    char* W = (char*)d_ws;
    unsigned short* xb  = (unsigned short*)(W);                    // 4 MB
    unsigned short* wqT = (unsigned short*)(W + (4ll  << 20));     // 1 MB
    unsigned short* wkT = (unsigned short*)(W + (5ll  << 20));     // 1 MB
    unsigned short* wvT = (unsigned short*)(W + (6ll  << 20));     // 1 MB
    unsigned short* woT = (unsigned short*)(W + (7ll  << 20));     // 1 MB
    unsigned short* qb  = (unsigned short*)(W + (8ll  << 20));     // 2 MB
    unsigned short* kb  = (unsigned short*)(W + (10ll << 20));     // 2 MB
    unsigned short* vt  = (unsigned short*)(W + (12ll << 20));     // 2 MB
    __half* E           = (__half*)(W + (14ll << 20));             // 32 MB
    float* u            = (float*)(W + (46ll << 20));              // 64 KB
    float* v            = (float*)(W + (46ll << 20) + 65536);      // 64 KB
    float* part         = (float*)(W + (47ll << 20));              // 4 MB
    unsigned short* o_p = (unsigned short*)(W + (51ll << 20));     // 2 MB

    convert_x<<<512, 256, 0, stream>>>(x, xb);
    transpose_all<<<dim3(32, 32, 4), 256, 0, stream>>>(Wq, Wk, Wv, Wo, wqT, wkT, wvT, woT);
    init_uv<<<64, 256, 0, stream>>>(u, v);
    mfma_qkv<<<dim3(4, 16, 3), 256, 0, stream>>>(xb, wqT, wkT, wvT, bq, bk, bv, qb, kb, vt);
    mfma_logits<<<dim3(8, 8, 16), 256, 0, stream>>>(qb, kb, E);
    for (int it = 0; it < N_ITERS; ++it) {
        sinkhorn_pass<<<dim3(64, 16), 256, 0, stream>>>(E, u, v, part);
        sinkhorn_merge<<<64, 256, 0, stream>>>(part, v);
    }
    attn_mfma<<<dim3(16, 16), 256, 0, stream>>>(E, u, v, vt, o_p);
    mfma_out<<<dim3(8, 16), 256, 0, stream>>>(o_p, woT, bo, out);
}